// Round 1
// baseline (16044.377 us; speedup 1.0000x reference)
//
#include <hip/hip_runtime.h>
#include <stdint.h>

#define T_SEQ 512
#define BATCH 128
#define HID 1024
#define LAYERS 4
#define BK 64
#define LDS_STRIDE 72   // 64 + 8 pad: b128 frag reads land at ~2-way bank aliasing (free)

typedef __attribute__((ext_vector_type(4))) float f32x4;
typedef __attribute__((ext_vector_type(8))) short s16x8;
typedef __attribute__((ext_vector_type(8))) unsigned short u16x8;

__device__ __forceinline__ unsigned short f2bf(float f) {
    unsigned int x = __builtin_bit_cast(unsigned int, f);
    unsigned int r = (x + 0x7fffu + ((x >> 16) & 1u)) >> 16;
    return (unsigned short)r;
}

// Convert weights fp32 -> bf16 into ws, merge biases. Runs every launch (ws re-poisoned).
__global__ void prep_kernel(const float* __restrict__ Wih, const float* __restrict__ Whh,
                            const float* __restrict__ bih, const float* __restrict__ bhh,
                            unsigned short* __restrict__ Wbf, float* __restrict__ bias) {
    int idx = blockIdx.x * blockDim.x + threadIdx.x;
    const int HH = HID * HID;
    if (idx < LAYERS * HH) {
        int layer = idx / HH;
        int off = idx - layer * HH;
        // layout: [layer][0]=W_ih, [layer][1]=W_hh, each HxH row-major [n][k]
        Wbf[(size_t)layer * 2 * HH + off]      = f2bf(Wih[idx]);
        Wbf[(size_t)layer * 2 * HH + HH + off] = f2bf(Whh[idx]);
    }
    if (idx < LAYERS * HID) bias[idx] = bih[idx] + bhh[idx];
}

// One wavefront stage s: cells (layer i, t = s - i) for i in 0..3, each a fused
// K=2048 GEMM: tanh( in(t) @ W_ih^T + h_i(t-1) @ W_hh^T + b_ih + b_hh ).
// in(t) = x[t] (layer 0, fp32->bf16 on the fly) or h_{i-1}(t) (bf16, prev parity).
// grid: (16 n-tiles, 2 m-tiles, 4 layers), block 256 (4 waves, 32x32 wave tiles).
__global__ __launch_bounds__(256) void cell_kernel(
        const float* __restrict__ x,
        const unsigned short* __restrict__ Wbf,
        const float* __restrict__ bias,
        unsigned short* __restrict__ hbf,   // [L][2 parity][B][H] bf16
        float* __restrict__ out,            // [T][B][H] fp32
        int s) {
    const int layer = blockIdx.z;
    const int tt = s - layer;
    if (tt < 0 || tt >= T_SEQ) return;
    const int par = s & 1, prev = par ^ 1;
    const int HH = HID * HID;

    __shared__ unsigned short As[64 * LDS_STRIDE];
    __shared__ unsigned short Bs[64 * LDS_STRIDE];

    const int tid = threadIdx.x;
    const int m0 = blockIdx.y * 64;
    const int n0 = blockIdx.x * 64;
    const int wave = tid >> 6, lane = tid & 63;
    const int wm = (wave >> 1) * 32, wn = (wave & 1) * 32;

    f32x4 acc[2][2];
    for (int f = 0; f < 2; ++f)
        for (int g = 0; g < 2; ++g)
            acc[f][g] = (f32x4){0.f, 0.f, 0.f, 0.f};

    // staging map: each thread stages 16 contiguous k-elements of one row
    const int srow = tid >> 2;          // 0..63
    const int skq  = (tid & 3) * 16;    // 0,16,32,48

    const int nphase = (tt == 0) ? 1 : 2;   // t==0: h(-1)=0, skip recurrent phase
    for (int ph = 0; ph < nphase; ++ph) {
        const unsigned short* Wp = Wbf + (size_t)layer * 2 * HH + (size_t)ph * HH;
        const float* xsrc = nullptr;
        const unsigned short* hsrc = nullptr;
        if (ph == 0) {
            if (layer == 0) xsrc = x + (size_t)tt * BATCH * HID;
            else hsrc = hbf + (size_t)((layer - 1) * 2 + prev) * BATCH * HID;
        } else {
            hsrc = hbf + (size_t)(layer * 2 + prev) * BATCH * HID;
        }

        for (int k0 = 0; k0 < HID; k0 += BK) {
            // ---- global loads into regs ----
            const unsigned short* wptr = Wp + (size_t)(n0 + srow) * HID + k0 + skq;
            u16x8 breg0 = *(const u16x8*)wptr;
            u16x8 breg1 = *(const u16x8*)(wptr + 8);

            u16x8 areg0, areg1;
            if (xsrc) {
                const float* ap = xsrc + (size_t)(m0 + srow) * HID + k0 + skq;
                f32x4 f0 = *(const f32x4*)(ap);
                f32x4 f1 = *(const f32x4*)(ap + 4);
                f32x4 f2 = *(const f32x4*)(ap + 8);
                f32x4 f3 = *(const f32x4*)(ap + 12);
                for (int j = 0; j < 4; ++j) {
                    areg0[j]     = f2bf(f0[j]);
                    areg0[4 + j] = f2bf(f1[j]);
                    areg1[j]     = f2bf(f2[j]);
                    areg1[4 + j] = f2bf(f3[j]);
                }
            } else {
                const unsigned short* ap = hsrc + (size_t)(m0 + srow) * HID + k0 + skq;
                areg0 = *(const u16x8*)(ap);
                areg1 = *(const u16x8*)(ap + 8);
            }

            __syncthreads();   // previous iter's LDS reads done
            *(u16x8*)&Bs[srow * LDS_STRIDE + skq]     = breg0;
            *(u16x8*)&Bs[srow * LDS_STRIDE + skq + 8] = breg1;
            *(u16x8*)&As[srow * LDS_STRIDE + skq]     = areg0;
            *(u16x8*)&As[srow * LDS_STRIDE + skq + 8] = areg1;
            __syncthreads();

            // ---- fragments + MFMA ----
            const int l15 = lane & 15;
            for (int kk = 0; kk < 2; ++kk) {
                const int kb = kk * 32 + ((lane >> 4) << 3);
                s16x8 a0 = *(const s16x8*)&As[(wm + 0  + l15) * LDS_STRIDE + kb];
                s16x8 a1 = *(const s16x8*)&As[(wm + 16 + l15) * LDS_STRIDE + kb];
                s16x8 b0 = *(const s16x8*)&Bs[(wn + 0  + l15) * LDS_STRIDE + kb];
                s16x8 b1 = *(const s16x8*)&Bs[(wn + 16 + l15) * LDS_STRIDE + kb];
                acc[0][0] = __builtin_amdgcn_mfma_f32_16x16x32_bf16(a0, b0, acc[0][0], 0, 0, 0);
                acc[0][1] = __builtin_amdgcn_mfma_f32_16x16x32_bf16(a0, b1, acc[0][1], 0, 0, 0);
                acc[1][0] = __builtin_amdgcn_mfma_f32_16x16x32_bf16(a1, b0, acc[1][0], 0, 0, 0);
                acc[1][1] = __builtin_amdgcn_mfma_f32_16x16x32_bf16(a1, b1, acc[1][1], 0, 0, 0);
            }
        }
    }

    // ---- epilogue: bias + tanh, write bf16 state (+ fp32 out for top layer) ----
    const int col = lane & 15;
    const int rq = (lane >> 4) << 2;
    unsigned short* hdst = hbf + (size_t)(layer * 2 + par) * BATCH * HID;
    for (int f = 0; f < 2; ++f) {
        for (int g = 0; g < 2; ++g) {
            const int gn = n0 + wn + g * 16 + col;
            const float bv = bias[layer * HID + gn];
            for (int r = 0; r < 4; ++r) {
                const int gm = m0 + wm + f * 16 + rq + r;
                float v = tanhf(acc[f][g][r] + bv);
                hdst[(size_t)gm * HID + gn] = f2bf(v);
                if (layer == LAYERS - 1)
                    out[((size_t)tt * BATCH + gm) * HID + gn] = v;
            }
        }
    }
}

extern "C" void kernel_launch(void* const* d_in, const int* in_sizes, int n_in,
                              void* d_out, int out_size, void* d_ws, size_t ws_size,
                              hipStream_t stream) {
    const float* x   = (const float*)d_in[0];
    const float* Wih = (const float*)d_in[1];
    const float* Whh = (const float*)d_in[2];
    const float* bih = (const float*)d_in[3];
    const float* bhh = (const float*)d_in[4];
    float* out = (float*)d_out;

    // ws layout: Wbf (L*2*H*H bf16 = 16 MiB) | bias (L*H fp32, pad to 64 KiB) | hbf (L*2*B*H bf16 = 2 MiB)
    unsigned short* Wbf = (unsigned short*)d_ws;
    float* bias = (float*)((char*)d_ws + (size_t)LAYERS * 2 * HID * HID * 2);
    unsigned short* hbf = (unsigned short*)((char*)d_ws + (size_t)LAYERS * 2 * HID * HID * 2 + 64 * 1024);

    // prep: 4M threads cover L*H*H
    {
        int total = LAYERS * HID * HID;
        int blocks = (total + 255) / 256;
        hipLaunchKernelGGL(prep_kernel, dim3(blocks), dim3(256), 0, stream,
                           Wih, Whh, bih, bhh, Wbf, bias);
    }

    // wavefront stages
    for (int s = 0; s < T_SEQ + LAYERS - 1; ++s) {
        hipLaunchKernelGGL(cell_kernel, dim3(16, 2, 4), dim3(256), 0, stream,
                           x, Wbf, bias, hbf, out, s);
    }
}